// Round 4
// baseline (113.436 us; speedup 1.0000x reference)
//
#include <hip/hip_runtime.h>
#include <hip/hip_bf16.h>

#define IMG 256
#define NG 1024
constexpr float PIX   = 1.0f / 256.0f;
constexpr float TTH   = 0.0001f;
constexpr float ACLIP = 0.99f;
constexpr float NEGHALF_LOG2E = -0.72134752044f;   // -0.5 * log2(e)

// ws layout (floats):
//   [0, 12288)      params[NG][12] = {mx,my,s00,soff,s11,la,cr,cg,cb,pad,pad,pad}
//                   (s** = inv-cov * -0.5*log2e ; la = log2(alpha)
//                    -> a_eff = exp2(dx(s00 dx + soff dy) + s11 dy^2 + la))
//   [12288, 16384)  bbox SoA: bmx[NG], bmy[NG], brx[NG], bry[NG]

__global__ __launch_bounds__(256)
void gs_prep(const float* __restrict__ mean, const float* __restrict__ cov,
             const float* __restrict__ color, const float* __restrict__ alpha,
             const float* __restrict__ depth, float* __restrict__ ws)
{
    __shared__ float sdepth[NG];
    const int tid = threadIdx.x;
    const int t   = blockIdx.x * 256 + tid;       // gaussian id (4 blocks x 256)

    for (int i = tid; i < NG; i += 256) sdepth[i] = depth[i];
    __syncthreads();

    const float d = sdepth[t];
    int rank = 0;
    const float4* s4 = (const float4*)sdepth;
    #pragma unroll 4
    for (int j4 = 0; j4 < NG / 4; ++j4) {
        const float4 dj = s4[j4];                 // broadcast read
        const int j = j4 * 4;
        rank += (dj.x < d) || (dj.x == d && (j + 0) < t);
        rank += (dj.y < d) || (dj.y == d && (j + 1) < t);
        rank += (dj.z < d) || (dj.z == d && (j + 2) < t);
        rank += (dj.w < d) || (dj.w == d && (j + 3) < t);
    }

    const float a  = cov[t * 4 + 0];
    const float b  = cov[t * 4 + 1];
    const float c  = cov[t * 4 + 2];
    const float dd = cov[t * 4 + 3];
    const float det    = a * dd - b * c;
    const float inv00  = dd / det;
    const float inv11  = a / det;
    const float invoff = -(b + c) / det;

    const float al = alpha[t];
    // cull cutoff: a_eff = al*exp(-q/2) < 1e-6  ->  q > 2*ln(al*1e6)
    float qcut = 2.0f * __logf(al * 1.0e6f + 1.0e-30f);
    qcut = fminf(fmaxf(qcut, 0.0f), 28.0f);
    const float rx = sqrtf(qcut * fmaxf(a,  0.0f));   // sqrt(q*Sxx)
    const float ry = sqrtf(qcut * fmaxf(dd, 0.0f));

    const float mx = mean[t * 2 + 0];
    const float my = mean[t * 2 + 1];

    float* o = ws + rank * 12;
    o[0] = mx;
    o[1] = my;
    o[2] = inv00  * NEGHALF_LOG2E;
    o[3] = invoff * NEGHALF_LOG2E;
    o[4] = inv11  * NEGHALF_LOG2E;
    o[5] = __log2f(al + 1.0e-30f);
    o[6] = color[t * 3 + 0];
    o[7] = color[t * 3 + 1];
    o[8] = color[t * 3 + 2];
    o[9] = 0.0f; o[10] = 0.0f; o[11] = 0.0f;

    float* bb = ws + NG * 12;
    bb[rank]          = mx;
    bb[NG + rank]     = my;
    bb[2 * NG + rank] = rx;
    bb[3 * NG + rank] = ry;
}

// 1024 blocks x 64 threads; one wave = one 8x8 pixel tile. No LDS, no barriers.
__global__ __launch_bounds__(64)
void gs_render(const float* __restrict__ ws, const float* __restrict__ bg,
               const float* __restrict__ topleft, float* __restrict__ out)
{
    const int lane = threadIdx.x;
    const int tile = blockIdx.x;                  // 32x32 tiles of 8x8 px
    const int tx = (tile & 31) * 8;
    const int ty = (tile >> 5) * 8;
    const int col = tx + (lane & 7);
    const int row = ty + (lane >> 3);
    const float tl0 = topleft[0], tl1 = topleft[1];
    const float px = ((float)col + 0.5f) * PIX - tl0;
    const float py = ((float)row + 0.5f) * PIX - tl1;
    const float cx = ((float)tx + 4.0f) * PIX - tl0;   // center of the 8x8 pixel-center box
    const float cy = ((float)ty + 4.0f) * PIX - tl1;
    const float hw = 3.5f * PIX;

    const float* bmx = ws + NG * 12;
    const float* bmy = bmx + NG;
    const float* brx = bmy + NG;
    const float* bry = brx + NG;

    float T = 1.0f, r = 0.0f, g = 0.0f, b = 0.0f;

    for (int c = 0; c < NG / 64; ++c) {
        if (__all(T <= TTH)) break;               // wave saturated

        const int gi = c * 64 + lane;             // coalesced, L2-resident
        const bool hit = (fabsf(bmx[gi] - cx) <= brx[gi] + hw) &&
                         (fabsf(bmy[gi] - cy) <= bry[gi] + hw);
        unsigned long long mask = __ballot(hit);  // wave-uniform
        if (!mask) continue;

        // software-pipelined bit loop; param index is wave-uniform -> scalar loads
        int j = __ffsll(mask) - 1; mask &= mask - 1;
        int gg = __builtin_amdgcn_readfirstlane(c * 64 + j);
        const float* gp = ws + gg * 12;
        float4 a0 = *(const float4*)(gp);         // mx,my,s00,soff
        float4 a1 = *(const float4*)(gp + 4);     // s11,la,cr,cg
        float  cb = gp[8];                        // cb

        for (;;) {
            const bool more = (mask != 0);        // wave-uniform branch
            float4 n0, n1; float ncb = 0.0f;
            if (more) {
                const int jn = __ffsll(mask) - 1; mask &= mask - 1;
                const int ng2 = __builtin_amdgcn_readfirstlane(c * 64 + jn);
                const float* np = ws + ng2 * 12;
                n0 = *(const float4*)(np);
                n1 = *(const float4*)(np + 4);
                ncb = np[8];
            }

            const float dx = px - a0.x;
            const float dy = py - a0.y;
            const float q  = dx * (a0.z * dx + a0.w * dy) + fmaf(a1.x, dy * dy, a1.y);
            const float aeff = fminf(exp2f(q), ACLIP);   // = min(alpha*exp(-quad/2), clip)
            const float w  = aeff * T;            // ungated: tail error <= 1e-4
            r = fmaf(w, a1.z, r);
            g = fmaf(w, a1.w, g);
            b = fmaf(w, cb, b);
            T = T - w;                            // == T*(1-aeff)

            if (!more) break;
            a0 = n0; a1 = n1; cb = ncb;
        }
    }

    const int p = row * 256 + col;
    const float* bgp = bg + p * 3;
    float* op = out + p * 3;
    op[0] = r + T * bgp[0];
    op[1] = g + T * bgp[1];
    op[2] = b + T * bgp[2];
}

extern "C" void kernel_launch(void* const* d_in, const int* in_sizes, int n_in,
                              void* d_out, int out_size, void* d_ws, size_t ws_size,
                              hipStream_t stream) {
    const float* mean    = (const float*)d_in[0];
    const float* cov     = (const float*)d_in[1];
    const float* color   = (const float*)d_in[2];
    const float* alpha   = (const float*)d_in[3];
    const float* depth   = (const float*)d_in[4];
    const float* bg      = (const float*)d_in[5];
    const float* topleft = (const float*)d_in[6];
    float* out = (float*)d_out;
    float* ws  = (float*)d_ws;                    // 64 KiB used

    gs_prep<<<4, 256, 0, stream>>>(mean, cov, color, alpha, depth, ws);
    gs_render<<<1024, 64, 0, stream>>>(ws, bg, topleft, out);
}

// Round 5
// 100.242 us; speedup vs baseline: 1.1316x; 1.1316x over previous
//
#include <hip/hip_runtime.h>
#include <hip/hip_bf16.h>

#define IMG 256
#define NG 1024
constexpr float PIX   = 1.0f / 256.0f;
constexpr float TTH   = 0.0001f;
constexpr float ACLIP = 0.99f;
constexpr float NEGHALF_LOG2E = -0.72134752044f;   // -0.5 * log2(e)

// ws layout (floats):
//   [0, 12288)      params[NG][12] = {mx,my,s00,soff,s11,la,cr,cg,cb,pad,pad,pad}
//                   (s** = inv-cov * -0.5*log2e ; la = log2(alpha)
//                    -> a_eff = exp2(dx*(s00 dx + soff dy) + s11 dy^2 + la))
//   [12288, 16384)  bbox AoS: float4 {mx,my,rx,ry} per gaussian (depth-sorted)

__global__ __launch_bounds__(256)
void gs_prep(const float* __restrict__ mean, const float* __restrict__ cov,
             const float* __restrict__ color, const float* __restrict__ alpha,
             const float* __restrict__ depth, float* __restrict__ ws)
{
    __shared__ float sdepth[NG];
    const int tid = threadIdx.x;
    const int t   = blockIdx.x * 256 + tid;       // gaussian id (4 blocks x 256)

    for (int i = tid; i < NG; i += 256) sdepth[i] = depth[i];
    __syncthreads();

    const float d = sdepth[t];
    int rank = 0;
    const float4* s4 = (const float4*)sdepth;
    #pragma unroll 4
    for (int j4 = 0; j4 < NG / 4; ++j4) {
        const float4 dj = s4[j4];                 // broadcast read
        const int j = j4 * 4;
        rank += (dj.x < d) || (dj.x == d && (j + 0) < t);
        rank += (dj.y < d) || (dj.y == d && (j + 1) < t);
        rank += (dj.z < d) || (dj.z == d && (j + 2) < t);
        rank += (dj.w < d) || (dj.w == d && (j + 3) < t);
    }

    const float a  = cov[t * 4 + 0];
    const float b  = cov[t * 4 + 1];
    const float c  = cov[t * 4 + 2];
    const float dd = cov[t * 4 + 3];
    const float det    = a * dd - b * c;
    const float inv00  = dd / det;
    const float inv11  = a / det;
    const float invoff = -(b + c) / det;

    const float al = alpha[t];
    // cull cutoff: a_eff = al*exp(-q/2) < 1e-6  ->  q > 2*ln(al*1e6)
    float qcut = 2.0f * __logf(al * 1.0e6f + 1.0e-30f);
    qcut = fminf(fmaxf(qcut, 0.0f), 28.0f);
    const float rx = sqrtf(qcut * fmaxf(a,  0.0f));   // sqrt(q*Sxx)
    const float ry = sqrtf(qcut * fmaxf(dd, 0.0f));

    const float mx = mean[t * 2 + 0];
    const float my = mean[t * 2 + 1];

    float* o = ws + rank * 12;
    o[0] = mx;
    o[1] = my;
    o[2] = inv00  * NEGHALF_LOG2E;
    o[3] = invoff * NEGHALF_LOG2E;
    o[4] = inv11  * NEGHALF_LOG2E;
    o[5] = __log2f(al + 1.0e-30f);
    o[6] = color[t * 3 + 0];
    o[7] = color[t * 3 + 1];
    o[8] = color[t * 3 + 2];
    o[9] = 0.0f; o[10] = 0.0f; o[11] = 0.0f;

    float4* bb4 = (float4*)(ws + NG * 12);
    bb4[rank] = make_float4(mx, my, rx, ry);
}

// 1024 blocks x 256 threads. Block = one 8x8 pixel tile; wave s composites
// depth segment s (256 gaussians) independently; exact combine via LDS.
__global__ __launch_bounds__(256)
void gs_render(const float* __restrict__ ws, const float* __restrict__ bg,
               const float* __restrict__ topleft, float* __restrict__ out)
{
    __shared__ float sC[4][4][64];                // [seg][r,g,b,T][pixel] = 4 KiB
    const int tid  = threadIdx.x;
    const int wave = tid >> 6;                    // = depth segment
    const int lane = tid & 63;

    const int tile = blockIdx.x;                  // 32x32 tiles of 8x8 px
    const int tx = (tile & 31) * 8;
    const int ty = (tile >> 5) * 8;
    const int col = tx + (lane & 7);
    const int row = ty + (lane >> 3);
    const float tl0 = topleft[0], tl1 = topleft[1];
    const float px = ((float)col + 0.5f) * PIX - tl0;
    const float py = ((float)row + 0.5f) * PIX - tl1;
    const float cx = ((float)tx + 4.0f) * PIX - tl0;   // center of 8x8 pixel-center box
    const float cy = ((float)ty + 4.0f) * PIX - tl1;
    const float hw = 3.5f * PIX;

    const float4* bb4 = (const float4*)(ws + NG * 12);

    float T = 1.0f, r = 0.0f, g = 0.0f, b = 0.0f;

    for (int c = 0; c < 4; ++c) {                 // 4 chunks of 64 per segment
        const int gi = wave * 256 + c * 64 + lane;
        const float4 bb = bb4[gi];                // coalesced 16B, L2-hot
        const bool hit = (fabsf(bb.x - cx) <= bb.z + hw) &&
                         (fabsf(bb.y - cy) <= bb.w + hw);
        unsigned long long mask = __ballot(hit);  // wave-uniform
        if (!mask) continue;

        // bit loop; param index wave-uniform -> scalar loads (TLP hides latency)
        int j = __ffsll(mask) - 1; mask &= mask - 1;
        int gg = __builtin_amdgcn_readfirstlane(wave * 256 + c * 64 + j);
        const float* gp = ws + gg * 12;
        float4 a0 = *(const float4*)(gp);         // mx,my,s00,soff
        float4 a1 = *(const float4*)(gp + 4);     // s11,la,cr,cg
        float  cb = gp[8];                        // cb

        for (;;) {
            const bool more = (mask != 0);        // wave-uniform
            float4 n0, n1; float ncb = 0.0f;
            if (more) {
                const int jn = __ffsll(mask) - 1; mask &= mask - 1;
                const int g2 = __builtin_amdgcn_readfirstlane(wave * 256 + c * 64 + jn);
                const float* np = ws + g2 * 12;
                n0 = *(const float4*)(np);
                n1 = *(const float4*)(np + 4);
                ncb = np[8];
            }

            const float dx = px - a0.x;
            const float dy = py - a0.y;
            const float q  = dx * (a0.z * dx + a0.w * dy) + fmaf(a1.x, dy * dy, a1.y);
            const float aeff = fminf(exp2f(q), ACLIP);   // = min(alpha*exp(-quad/2), clip)
            const float w  = aeff * T;            // ungated (tail <= 1e-4)
            r = fmaf(w, a1.z, r);
            g = fmaf(w, a1.w, g);
            b = fmaf(w, cb, b);
            T = T - w;                            // == T*(1-aeff)

            if (!more) break;
            a0 = n0; a1 = n1; cb = ncb;
        }
    }

    sC[wave][0][lane] = r;
    sC[wave][1][lane] = g;
    sC[wave][2][lane] = b;
    sC[wave][3][lane] = T;
    __syncthreads();

    if (wave == 0) {
        const float r1 = sC[1][0][lane], g1 = sC[1][1][lane],
                    b1 = sC[1][2][lane], t1 = sC[1][3][lane];
        const float r2 = sC[2][0][lane], g2 = sC[2][1][lane],
                    b2 = sC[2][2][lane], t2 = sC[2][3][lane];
        const float r3 = sC[3][0][lane], g3 = sC[3][1][lane],
                    b3 = sC[3][2][lane], t3 = sC[3][3][lane];

        // C = C0 + T0*(C1 + T1*(C2 + T2*C3)); T = T0*T1*T2*T3
        const float R  = fmaf(T, fmaf(t1, fmaf(t2, r3, r2), r1), r);
        const float G  = fmaf(T, fmaf(t1, fmaf(t2, g3, g2), g1), g);
        const float B  = fmaf(T, fmaf(t1, fmaf(t2, b3, b2), b1), b);
        const float Tf = T * t1 * t2 * t3;

        const int p = row * 256 + col;
        const float* bgp = bg + p * 3;
        float* op = out + p * 3;
        op[0] = R + Tf * bgp[0];
        op[1] = G + Tf * bgp[1];
        op[2] = B + Tf * bgp[2];
    }
}

extern "C" void kernel_launch(void* const* d_in, const int* in_sizes, int n_in,
                              void* d_out, int out_size, void* d_ws, size_t ws_size,
                              hipStream_t stream) {
    const float* mean    = (const float*)d_in[0];
    const float* cov     = (const float*)d_in[1];
    const float* color   = (const float*)d_in[2];
    const float* alpha   = (const float*)d_in[3];
    const float* depth   = (const float*)d_in[4];
    const float* bg      = (const float*)d_in[5];
    const float* topleft = (const float*)d_in[6];
    float* out = (float*)d_out;
    float* ws  = (float*)d_ws;                    // 64 KiB used

    gs_prep<<<4, 256, 0, stream>>>(mean, cov, color, alpha, depth, ws);
    gs_render<<<1024, 256, 0, stream>>>(ws, bg, topleft, out);
}

// Round 6
// 81.412 us; speedup vs baseline: 1.3934x; 1.2313x over previous
//
#include <hip/hip_runtime.h>
#include <hip/hip_bf16.h>

#define IMG 256
#define NG 1024
constexpr float PIX   = 1.0f / 256.0f;
constexpr float TTH   = 0.0001f;
constexpr float ACLIP = 0.99f;
constexpr float NEGHALF_LOG2E = -0.72134752044f;   // -0.5 * log2(e)

// ws layout (floats):
//   [0, 12288)      params[NG][12] = {mx,my,s00,soff,s11,la,cr,cg,cb,pad,pad,pad}
//                   (s** = inv-cov * -0.5*log2e ; la = log2(alpha)
//                    -> a_eff = exp2(dx*(s00 dx + soff dy) + s11 dy^2 + la))
//   [12288, 16384)  bbox AoS: float4 {mx,my,rx,ry} per gaussian (depth-sorted)

// 16 blocks x 256 threads; block owns 64 gaussians; rank scan split 4-ways.
__global__ __launch_bounds__(256)
void gs_prep(const float* __restrict__ mean, const float* __restrict__ cov,
             const float* __restrict__ color, const float* __restrict__ alpha,
             const float* __restrict__ depth, float* __restrict__ ws)
{
    __shared__ float sdepth[NG];
    __shared__ int   spart[4][64];
    const int tid   = threadIdx.x;
    const int lane64 = tid & 63;
    const int seg   = tid >> 6;                   // scan quarter
    const int g     = blockIdx.x * 64 + lane64;   // gaussian id

    for (int i = tid; i < NG; i += 256) sdepth[i] = depth[i];
    __syncthreads();

    const float d = sdepth[g];
    int rank = 0;
    const float4* s4 = (const float4*)sdepth;
    const int base4 = seg * 64;
    #pragma unroll 8
    for (int k = 0; k < 64; ++k) {
        const int j4 = base4 + k;
        const float4 dj = s4[j4];                 // broadcast read
        const int j = j4 * 4;
        rank += (dj.x < d) || (dj.x == d && (j + 0) < g);
        rank += (dj.y < d) || (dj.y == d && (j + 1) < g);
        rank += (dj.z < d) || (dj.z == d && (j + 2) < g);
        rank += (dj.w < d) || (dj.w == d && (j + 3) < g);
    }
    spart[seg][lane64] = rank;
    __syncthreads();

    if (seg == 0) {
        const int r = spart[0][lane64] + spart[1][lane64]
                    + spart[2][lane64] + spart[3][lane64];

        const float a  = cov[g * 4 + 0];
        const float b  = cov[g * 4 + 1];
        const float c  = cov[g * 4 + 2];
        const float dd = cov[g * 4 + 3];
        const float det    = a * dd - b * c;
        const float inv00  = dd / det;
        const float inv11  = a / det;
        const float invoff = -(b + c) / det;

        const float al = alpha[g];
        // cull cutoff: a_eff = al*exp(-q/2) < 1e-6  ->  q > 2*ln(al*1e6)
        float qcut = 2.0f * __logf(al * 1.0e6f + 1.0e-30f);
        qcut = fminf(fmaxf(qcut, 0.0f), 28.0f);
        const float rx = sqrtf(qcut * fmaxf(a,  0.0f));
        const float ry = sqrtf(qcut * fmaxf(dd, 0.0f));

        const float mx = mean[g * 2 + 0];
        const float my = mean[g * 2 + 1];

        float* o = ws + r * 12;
        o[0] = mx;
        o[1] = my;
        o[2] = inv00  * NEGHALF_LOG2E;
        o[3] = invoff * NEGHALF_LOG2E;
        o[4] = inv11  * NEGHALF_LOG2E;
        o[5] = __log2f(al + 1.0e-30f);
        o[6] = color[g * 3 + 0];
        o[7] = color[g * 3 + 1];
        o[8] = color[g * 3 + 2];
        o[9] = 0.0f; o[10] = 0.0f; o[11] = 0.0f;

        float4* bb4 = (float4*)(ws + NG * 12);
        bb4[r] = make_float4(mx, my, rx, ry);
    }
}

// 1024 blocks x 512 threads. Block = one 8x8 tile; wave s composites depth
// segment s (128 gaussians) independently; exact combine via LDS.
__global__ __launch_bounds__(512, 8)
void gs_render(const float* __restrict__ ws, const float* __restrict__ bg,
               const float* __restrict__ topleft, float* __restrict__ out)
{
    __shared__ float sC[8][4][64];                // [seg][r,g,b,T][pixel] = 8 KiB
    const int tid  = threadIdx.x;
    const int wave = tid >> 6;                    // = depth segment (0..7)
    const int lane = tid & 63;

    const int tile = blockIdx.x;                  // 32x32 tiles of 8x8 px
    const int tx = (tile & 31) * 8;
    const int ty = (tile >> 5) * 8;
    const int col = tx + (lane & 7);
    const int row = ty + (lane >> 3);
    const float tl0 = topleft[0], tl1 = topleft[1];
    const float px = ((float)col + 0.5f) * PIX - tl0;
    const float py = ((float)row + 0.5f) * PIX - tl1;
    const float cx = ((float)tx + 4.0f) * PIX - tl0;   // center of 8x8 pixel-center box
    const float cy = ((float)ty + 4.0f) * PIX - tl1;
    const float hw = 3.5f * PIX;

    const float4* bb4 = (const float4*)(ws + NG * 12);

    float T = 1.0f, r = 0.0f, g = 0.0f, b = 0.0f;

    for (int c = 0; c < 2; ++c) {                 // 2 chunks of 64 per segment
        if (__all(T <= TTH)) break;

        const int gi = wave * 128 + c * 64 + lane;
        const float4 bb = bb4[gi];                // coalesced 16B, L2-hot
        const bool hit = (fabsf(bb.x - cx) <= bb.z + hw) &&
                         (fabsf(bb.y - cy) <= bb.w + hw);
        unsigned long long mask = __ballot(hit);  // wave-uniform
        if (!mask) continue;

        // bit loop; param index wave-uniform -> scalar loads (TLP hides latency)
        int j = __ffsll(mask) - 1; mask &= mask - 1;
        int gg = __builtin_amdgcn_readfirstlane(wave * 128 + c * 64 + j);
        const float* gp = ws + gg * 12;
        float4 a0 = *(const float4*)(gp);         // mx,my,s00,soff
        float4 a1 = *(const float4*)(gp + 4);     // s11,la,cr,cg
        float  cb = gp[8];                        // cb

        for (;;) {
            const bool more = (mask != 0);        // wave-uniform
            float4 n0, n1; float ncb = 0.0f;
            if (more) {
                const int jn = __ffsll(mask) - 1; mask &= mask - 1;
                const int g2 = __builtin_amdgcn_readfirstlane(wave * 128 + c * 64 + jn);
                const float* np = ws + g2 * 12;
                n0 = *(const float4*)(np);
                n1 = *(const float4*)(np + 4);
                ncb = np[8];
            }

            const float dx = px - a0.x;
            const float dy = py - a0.y;
            const float q  = dx * (a0.z * dx + a0.w * dy) + fmaf(a1.x, dy * dy, a1.y);
            const float aeff = fminf(exp2f(q), ACLIP);   // = min(alpha*exp(-quad/2), clip)
            const float w  = aeff * T;            // ungated (tail <= 1e-4)
            r = fmaf(w, a1.z, r);
            g = fmaf(w, a1.w, g);
            b = fmaf(w, cb, b);
            T = T - w;                            // == T*(1-aeff)

            if (!more) break;
            a0 = n0; a1 = n1; cb = ncb;
        }
    }

    sC[wave][0][lane] = r;
    sC[wave][1][lane] = g;
    sC[wave][2][lane] = b;
    sC[wave][3][lane] = T;
    __syncthreads();

    if (wave == 0) {
        float R = r, G = g, B = b, Tf = T;
        #pragma unroll
        for (int s = 1; s < 8; ++s) {
            R  = fmaf(Tf, sC[s][0][lane], R);
            G  = fmaf(Tf, sC[s][1][lane], G);
            B  = fmaf(Tf, sC[s][2][lane], B);
            Tf *= sC[s][3][lane];
        }

        const int p = row * 256 + col;
        const float* bgp = bg + p * 3;
        float* op = out + p * 3;
        op[0] = R + Tf * bgp[0];
        op[1] = G + Tf * bgp[1];
        op[2] = B + Tf * bgp[2];
    }
}

extern "C" void kernel_launch(void* const* d_in, const int* in_sizes, int n_in,
                              void* d_out, int out_size, void* d_ws, size_t ws_size,
                              hipStream_t stream) {
    const float* mean    = (const float*)d_in[0];
    const float* cov     = (const float*)d_in[1];
    const float* color   = (const float*)d_in[2];
    const float* alpha   = (const float*)d_in[3];
    const float* depth   = (const float*)d_in[4];
    const float* bg      = (const float*)d_in[5];
    const float* topleft = (const float*)d_in[6];
    float* out = (float*)d_out;
    float* ws  = (float*)d_ws;                    // 64 KiB used

    gs_prep<<<16, 256, 0, stream>>>(mean, cov, color, alpha, depth, ws);
    gs_render<<<1024, 512, 0, stream>>>(ws, bg, topleft, out);
}

// Round 7
// 77.167 us; speedup vs baseline: 1.4700x; 1.0550x over previous
//
#include <hip/hip_runtime.h>
#include <hip/hip_bf16.h>

#define IMG 256
#define NG 1024
constexpr float PIX   = 1.0f / 256.0f;
constexpr float TTH   = 0.0001f;
constexpr float ACLIP = 0.99f;
constexpr float NEGHALF_LOG2E = -0.72134752044f;   // -0.5 * log2(e)

// ws layout (floats):
//   [0, 12288)      params[NG][12] = {mx,my,s00,soff,s11,la,cr,cg,cb,pad,pad,pad}
//                   (s** = inv-cov * -0.5*log2e ; la = log2(alpha)
//                    -> a_eff = exp2(dx*(s00 dx + soff dy) + s11 dy^2 + la))
//   [12288, 16384)  bbox AoS: float4 {mx,my,rx,ry} per gaussian (depth-sorted)

// 16 blocks x 512 threads; block owns 64 gaussians; rank scan split 8-ways.
__global__ __launch_bounds__(512)
void gs_prep(const float* __restrict__ mean, const float* __restrict__ cov,
             const float* __restrict__ color, const float* __restrict__ alpha,
             const float* __restrict__ depth, float* __restrict__ ws)
{
    __shared__ float sdepth[NG];
    __shared__ int   spart[8][64];
    const int tid    = threadIdx.x;
    const int lane64 = tid & 63;
    const int seg    = tid >> 6;                  // scan eighth (0..7)
    const int g      = blockIdx.x * 64 + lane64;  // gaussian id

    for (int i = tid; i < NG; i += 512) sdepth[i] = depth[i];
    __syncthreads();

    const float d = sdepth[g];
    int rank = 0;
    const float4* s4 = (const float4*)sdepth;
    const int base4 = seg * 32;
    #pragma unroll 8
    for (int k = 0; k < 32; ++k) {
        const int j4 = base4 + k;
        const float4 dj = s4[j4];                 // broadcast read
        const int j = j4 * 4;
        rank += (dj.x < d) || (dj.x == d && (j + 0) < g);
        rank += (dj.y < d) || (dj.y == d && (j + 1) < g);
        rank += (dj.z < d) || (dj.z == d && (j + 2) < g);
        rank += (dj.w < d) || (dj.w == d && (j + 3) < g);
    }
    spart[seg][lane64] = rank;
    __syncthreads();

    if (seg == 0) {
        int r = 0;
        #pragma unroll
        for (int s = 0; s < 8; ++s) r += spart[s][lane64];

        const float a  = cov[g * 4 + 0];
        const float b  = cov[g * 4 + 1];
        const float c  = cov[g * 4 + 2];
        const float dd = cov[g * 4 + 3];
        const float det    = a * dd - b * c;
        const float inv00  = dd / det;
        const float inv11  = a / det;
        const float invoff = -(b + c) / det;

        const float al = alpha[g];
        // cull cutoff: a_eff = al*exp(-q/2) < 1e-5  ->  q > 2*ln(al*1e5)
        float qcut = 2.0f * __logf(al * 1.0e5f + 1.0e-30f);
        qcut = fminf(fmaxf(qcut, 0.0f), 24.0f);
        const float rx = sqrtf(qcut * fmaxf(a,  0.0f));
        const float ry = sqrtf(qcut * fmaxf(dd, 0.0f));

        const float mx = mean[g * 2 + 0];
        const float my = mean[g * 2 + 1];

        float* o = ws + r * 12;
        o[0] = mx;
        o[1] = my;
        o[2] = inv00  * NEGHALF_LOG2E;
        o[3] = invoff * NEGHALF_LOG2E;
        o[4] = inv11  * NEGHALF_LOG2E;
        o[5] = __log2f(al + 1.0e-30f);
        o[6] = color[g * 3 + 0];
        o[7] = color[g * 3 + 1];
        o[8] = color[g * 3 + 2];
        o[9] = 0.0f; o[10] = 0.0f; o[11] = 0.0f;

        float4* bb4 = (float4*)(ws + NG * 12);
        bb4[r] = make_float4(mx, my, rx, ry);
    }
}

// 1024 blocks x 512 threads. Block = one 8x8 tile; wave s composites depth
// segment s (128 gaussians, 2 chunks of 64) independently; exact LDS combine.
__global__ __launch_bounds__(512, 8)
void gs_render(const float* __restrict__ ws, const float* __restrict__ bg,
               const float* __restrict__ topleft, float* __restrict__ out)
{
    __shared__ float sC[8][4][64];                // [seg][r,g,b,T][pixel] = 8 KiB
    __shared__ float sP[2][4][64];                // level-1 partials = 2 KiB
    const int tid  = threadIdx.x;
    const int wave = tid >> 6;                    // = depth segment (0..7)
    const int lane = tid & 63;

    const int tile = blockIdx.x;                  // 32x32 tiles of 8x8 px
    const int tx = (tile & 31) * 8;
    const int ty = (tile >> 5) * 8;
    const int col = tx + (lane & 7);
    const int row = ty + (lane >> 3);
    const float tl0 = topleft[0], tl1 = topleft[1];
    const float px = ((float)col + 0.5f) * PIX - tl0;
    const float py = ((float)row + 0.5f) * PIX - tl1;
    const float cx = ((float)tx + 4.0f) * PIX - tl0;   // center of 8x8 pixel-center box
    const float cy = ((float)ty + 4.0f) * PIX - tl1;
    const float hw = 3.5f * PIX;

    const float4* bb4 = (const float4*)(ws + NG * 12);

    // prefetch both chunk bboxes (independent loads, latency overlapped)
    const int g0 = wave * 128 + lane;
    const float4 bbA = bb4[g0];
    const float4 bbB = bb4[g0 + 64];

    const bool hitA = (fabsf(bbA.x - cx) <= bbA.z + hw) &&
                      (fabsf(bbA.y - cy) <= bbA.w + hw);
    const bool hitB = (fabsf(bbB.x - cx) <= bbB.z + hw) &&
                      (fabsf(bbB.y - cy) <= bbB.w + hw);
    unsigned long long maskA = __ballot(hitA);
    unsigned long long maskB = __ballot(hitB);

    float T = 1.0f, r = 0.0f, g = 0.0f, b = 0.0f;

    #pragma unroll
    for (int c = 0; c < 2; ++c) {
        unsigned long long mask = c ? maskB : maskA;
        if (!mask) continue;
        const int cbase = wave * 128 + c * 64;

        // software-pipelined bit loop; param index wave-uniform -> scalar loads
        int j = __ffsll(mask) - 1; mask &= mask - 1;
        int gg = __builtin_amdgcn_readfirstlane(cbase + j);
        const float* gp = ws + gg * 12;
        float4 a0 = *(const float4*)(gp);         // mx,my,s00,soff
        float4 a1 = *(const float4*)(gp + 4);     // s11,la,cr,cg
        float  cb = gp[8];                        // cb

        for (;;) {
            const bool more = (mask != 0);        // wave-uniform
            float4 n0, n1; float ncb = 0.0f;
            if (more) {
                const int jn = __ffsll(mask) - 1; mask &= mask - 1;
                const int g2 = __builtin_amdgcn_readfirstlane(cbase + jn);
                const float* np = ws + g2 * 12;
                n0 = *(const float4*)(np);
                n1 = *(const float4*)(np + 4);
                ncb = np[8];
            }

            const float dx = px - a0.x;
            const float dy = py - a0.y;
            const float q  = dx * (a0.z * dx + a0.w * dy) + fmaf(a1.x, dy * dy, a1.y);
            const float aeff = fminf(exp2f(q), ACLIP);   // = min(alpha*exp(-quad/2), clip)
            const float w  = aeff * T;            // ungated (tail <= 1e-4)
            r = fmaf(w, a1.z, r);
            g = fmaf(w, a1.w, g);
            b = fmaf(w, cb, b);
            T = T - w;                            // == T*(1-aeff)

            if (!more) break;
            a0 = n0; a1 = n1; cb = ncb;
        }
    }

    sC[wave][0][lane] = r;
    sC[wave][1][lane] = g;
    sC[wave][2][lane] = b;
    sC[wave][3][lane] = T;
    __syncthreads();

    // level 1: wave w in {0,1} combines segments 4w..4w+3
    if (wave < 2) {
        const int s0 = wave * 4;
        float R = sC[s0][0][lane], G = sC[s0][1][lane],
              B = sC[s0][2][lane], Tf = sC[s0][3][lane];
        #pragma unroll
        for (int s = 1; s < 4; ++s) {
            R  = fmaf(Tf, sC[s0 + s][0][lane], R);
            G  = fmaf(Tf, sC[s0 + s][1][lane], G);
            B  = fmaf(Tf, sC[s0 + s][2][lane], B);
            Tf *= sC[s0 + s][3][lane];
        }
        sP[wave][0][lane] = R;
        sP[wave][1][lane] = G;
        sP[wave][2][lane] = B;
        sP[wave][3][lane] = Tf;
    }
    __syncthreads();

    // level 2: wave 0 merges the two partials, blends bg, stores
    if (wave == 0) {
        const float R0 = sP[0][0][lane], G0 = sP[0][1][lane],
                    B0 = sP[0][2][lane], T0 = sP[0][3][lane];
        const float R  = fmaf(T0, sP[1][0][lane], R0);
        const float G  = fmaf(T0, sP[1][1][lane], G0);
        const float B  = fmaf(T0, sP[1][2][lane], B0);
        const float Tf = T0 * sP[1][3][lane];

        const int p = row * 256 + col;
        const float* bgp = bg + p * 3;
        float* op = out + p * 3;
        op[0] = R + Tf * bgp[0];
        op[1] = G + Tf * bgp[1];
        op[2] = B + Tf * bgp[2];
    }
}

extern "C" void kernel_launch(void* const* d_in, const int* in_sizes, int n_in,
                              void* d_out, int out_size, void* d_ws, size_t ws_size,
                              hipStream_t stream) {
    const float* mean    = (const float*)d_in[0];
    const float* cov     = (const float*)d_in[1];
    const float* color   = (const float*)d_in[2];
    const float* alpha   = (const float*)d_in[3];
    const float* depth   = (const float*)d_in[4];
    const float* bg      = (const float*)d_in[5];
    const float* topleft = (const float*)d_in[6];
    float* out = (float*)d_out;
    float* ws  = (float*)d_ws;                    // 64 KiB used

    gs_prep<<<16, 512, 0, stream>>>(mean, cov, color, alpha, depth, ws);
    gs_render<<<1024, 512, 0, stream>>>(ws, bg, topleft, out);
}